// Round 3
// baseline (474.924 us; speedup 1.0000x reference)
//
#include <hip/hip_runtime.h>
#include <stdint.h>

#define NN 32
#define CI 256
#define CO 256
#define HH 56
#define WW 56
#define CNT (NN*HH*WW)

typedef int i32x4 __attribute__((ext_vector_type(4)));

// ======== 1. prep: weight-quant (blocks 0..255) + channel stats (256..2303)
__global__ void prep_kernel(const float* __restrict__ w,
                            const float* __restrict__ x,
                            int8_t* __restrict__ wT,
                            float* __restrict__ qscale,
                            double* __restrict__ part) {
    const int bid = blockIdx.x;
    if (bid < 256) {
        // ---- weight quant: per-co int8, layout [tap][chunk][co][ci64]
        const int co = bid;
        const float* wp = w + (size_t)co * 2304;
        float v[9], m = 0.f;
#pragma unroll
        for (int it = 0; it < 9; ++it) {
            v[it] = wp[threadIdx.x + it * 256];
            m = fmaxf(m, fabsf(v[it]));
        }
        for (int off = 32; off > 0; off >>= 1) m = fmaxf(m, __shfl_down(m, off, 64));
        __shared__ float redf[4];
        __shared__ float qsh;
        int wid = threadIdx.x >> 6, lane = threadIdx.x & 63;
        if (lane == 0) redf[wid] = m;
        __syncthreads();
        if (threadIdx.x == 0) {
            float mx = fmaxf(fmaxf(redf[0], redf[1]), fmaxf(redf[2], redf[3]));
            float q = (mx > 0.f) ? mx / 127.f : 1.f;
            qsh = q;
            qscale[co] = q;
        }
        __syncthreads();
        const float q = qsh;
#pragma unroll
        for (int it = 0; it < 9; ++it) {
            int idx = threadIdx.x + it * 256;
            int ci = idx / 9, tap = idx % 9;
            int chunk = ci >> 6, cis = ci & 63;
            int iq = __float2int_rn(v[it] / q);
            iq = iq > 127 ? 127 : (iq < -127 ? -127 : iq);
            wT[((size_t)(tap * 4 + chunk) * 256 + co) * 64 + cis] = (int8_t)iq;
        }
    } else {
        // ---- per-channel stats partials, 8-way split over n (4 images each)
        const int idx = bid - 256;
        const int c = idx & 255, sp = idx >> 8;
        double s = 0.0, ss = 0.0;
        const size_t base = ((size_t)(sp * 4) * CI + c) * 3136;
        for (int i = threadIdx.x; i < 4 * 784; i += 256) {
            int nl = i / 784, qq = i % 784;
            const float4 v = *(const float4*)(x + base + (size_t)nl * CI * 3136 + qq * 4);
            double a = v.x, b = v.y, cc = v.z, d = v.w;
            s  += (a + b) + (cc + d);
            ss += (a * a + b * b) + (cc * cc + d * d);
        }
        for (int off = 32; off > 0; off >>= 1) {
            s  += __shfl_down(s, off, 64);
            ss += __shfl_down(ss, off, 64);
        }
        __shared__ double redd[8];
        int wid = threadIdx.x >> 6, lane = threadIdx.x & 63;
        if (lane == 0) { redd[wid] = s; redd[4 + wid] = ss; }
        __syncthreads();
        if (threadIdx.x == 0) {
            part[(sp * 256 + c) * 2]     = (redd[0] + redd[1]) + (redd[2] + redd[3]);
            part[(sp * 256 + c) * 2 + 1] = (redd[4] + redd[5]) + (redd[6] + redd[7]);
        }
    }
}

// ======== 2. fused ternarize + implicit-GEMM conv ========================
// grid 896 (XCD-swizzled); block 256 = 4 waves; tile 128co x (4 rows x 64w)
// B built IN-KERNEL: x (L3-resident) -> f64 BN+sign -> int8 LDS, chunk-pipelined.
// LDS slot(row,s,wp) strides chosen bank-shifting: row*4624, s*1168, wp*16.
#define BUF_B 27776                       // bytes per B buffer (max slot 27775)
#define SLOT(row, s, wp) ((row) * 4624 + (s) * 1168 + (wp) * 16)

// issue global loads for one ci64-chunk into registers (6 quads/thread max)
__device__ __forceinline__ void loadf(const float* __restrict__ xb, int chunk,
                                      int h0, int tid, float4 (&f)[6][4]) {
    const float* cb = xb + (size_t)chunk * 64 * 3136;
#pragma unroll
    for (int k = 0; k < 6; ++k) {
        if (k < 5 || tid < 64) {
            int q = tid + k * 256;                  // 0..1343
            int ci4 = q / 84, rem = q - ci4 * 84;
            int row = rem / 14, w4 = rem - row * 14;
            int h = h0 - 1 + row;
            if ((unsigned)h < 56u) {
#pragma unroll
                for (int u = 0; u < 4; ++u)
                    f[k][u] = *(const float4*)(cb + (size_t)(ci4 * 4 + u) * 3136 + h * 56 + w4 * 4);
            }
        }
    }
}

// ternarize registers -> packed int8 words -> LDS buffer
__device__ __forceinline__ void transf(float4 (&f)[6][4],
                                       const double* __restrict__ Ssc,
                                       const double* __restrict__ Ssh,
                                       int chunk, int h0, int tid,
                                       int8_t* __restrict__ lbuf) {
    const int cbase = chunk * 64;
#pragma unroll
    for (int k = 0; k < 6; ++k) {
        if (k < 5 || tid < 64) {
            int q = tid + k * 256;
            int ci4 = q / 84, rem = q - ci4 * 84;
            int row = rem / 14, w4 = rem - row * 14;
            if ((unsigned)(h0 - 1 + row) < 56u) {
                int words[4] = {0, 0, 0, 0};
#pragma unroll
                for (int u = 0; u < 4; ++u) {
                    const double sc = Ssc[cbase + ci4 * 4 + u];
                    const double sh = Ssh[cbase + ci4 * 4 + u];
                    const float4 v = f[k][u];
                    const float vv[4] = {v.x, v.y, v.z, v.w};
#pragma unroll
                    for (int j = 0; j < 4; ++j) {
                        int b = (fma(sc, (double)vv[j], sh) > 0.0) ? 0x01 : 0xFF;
                        words[j] |= b << (8 * u);
                    }
                }
                const int base = SLOT(row, ci4 >> 2, 0) + (ci4 & 3) * 4;
#pragma unroll
                for (int j = 0; j < 4; ++j)
                    *(int*)&lbuf[base + (w4 * 4 + 1 + j) * 16] = words[j];
            }
        }
    }
}

__launch_bounds__(256, 2)
__global__ void conv_kernel(const int8_t* __restrict__ wT,
                            const float* __restrict__ x,
                            const double* __restrict__ part,
                            const float* __restrict__ gamma,
                            const float* __restrict__ beta,
                            const float* __restrict__ bias,
                            const float* __restrict__ qscale,
                            float* __restrict__ out) {
    // bijective XCD swizzle: 112 blocks per XCD -> 4 contiguous images each
    const int bid  = blockIdx.x;
    const int lin  = (bid & 7) * 112 + (bid >> 3);
    const int co_t = lin & 1;
    const int yb   = (lin >> 1) % 14;
    const int n    = lin / 28;
    const int h0   = yb * 4;

    const int tid  = threadIdx.x;
    const int lane = tid & 63, wid = tid >> 6;
    const int l15 = lane & 15, qd = lane >> 4;
    const int m_off = (wid & 1) * 64;
    const int rs = (wid >> 1) * 2;                 // wave's first output row
    const int aoff = l15 * 64 + qd * 16;           // per-lane A offset

    __shared__ __align__(16) int8_t Bsh[2 * BUF_B];
    __shared__ double Ssc[256], Ssh[256];

    // ---- per-block stats finalize (scale/shift per channel, f64)
    {
        const int c = tid;
        double S = 0.0, SS = 0.0;
#pragma unroll
        for (int sp = 0; sp < 8; ++sp) {
            S  += part[(sp * 256 + c) * 2];
            SS += part[(sp * 256 + c) * 2 + 1];
        }
        double mean = S / (double)CNT;
        double var  = SS / (double)CNT - mean * mean;
        double invstd = 1.0 / sqrt(var + 1e-4);
        double scale = (double)gamma[c] * invstd;
        Ssc[c] = scale;
        Ssh[c] = (double)beta[c] - mean * scale;
    }
    // ---- zero both B buffers (pads + halo rows stay zero forever)
    {
        i32x4 z = {0, 0, 0, 0};
        for (int p = tid; p < 2 * BUF_B / 16; p += 256)
            ((i32x4*)Bsh)[p] = z;
    }

    i32x4 acc[4][4][2];
#pragma unroll
    for (int i = 0; i < 4; ++i)
#pragma unroll
        for (int j = 0; j < 4; ++j)
#pragma unroll
            for (int r = 0; r < 2; ++r) acc[i][j][r] = (i32x4){0, 0, 0, 0};

    const float* xb = x + (size_t)n * CI * 3136;

#define LOADA(dst, cc_, tap_) do {                                              \
    const int8_t* ap_ = wT +                                                    \
        (((size_t)((tap_) * 4 + (cc_)) * 256 + co_t * 128 + m_off) << 6) + aoff;\
    dst[0] = *(const i32x4*)(ap_);                                              \
    dst[1] = *(const i32x4*)(ap_ + 1024);                                       \
    dst[2] = *(const i32x4*)(ap_ + 2048);                                       \
    dst[3] = *(const i32x4*)(ap_ + 3072);                                       \
} while (0)

    float4 f[6][4];
    i32x4 a[2][4];

    loadf(xb, 0, h0, tid, f);                      // x loads for chunk 0
    __syncthreads();                               // Ssc/Ssh + zeros visible
    transf(f, Ssc, Ssh, 0, h0, tid, Bsh);          // build buf0
    loadf(xb, 1, h0, tid, f);                      // x loads for chunk 1
    LOADA(a[0], 0, 0);

    for (int c2 = 0; c2 < 2; ++c2) {
#pragma unroll
        for (int cc = 0; cc < 2; ++cc) {
            const int c = c2 * 2 + cc;
            __syncthreads();                       // buf[cc] ready; buf[cc^1] free
            if (c < 3) transf(f, Ssc, Ssh, c + 1, h0, tid, Bsh + (cc ^ 1) * BUF_B);
            if (c < 2) loadf(xb, c + 2, h0, tid, f);
            const int8_t* lb = Bsh + cc * BUF_B;
#pragma unroll
            for (int tap = 0; tap < 9; ++tap) {
                const int kh = tap / 3, kw = tap % 3;
                const int cur = (cc * 9 + tap) & 1, nxt = cur ^ 1;  // static
                i32x4 b[4][2];
#pragma unroll
                for (int j = 0; j < 4; ++j) {
                    const int wp = j * 16 + l15 + kw;
#pragma unroll
                    for (int r = 0; r < 2; ++r)
                        b[j][r] = *(const i32x4*)&lb[SLOT(rs + r + kh, qd, wp)];
                }
                if (tap < 8)      LOADA(a[nxt], c, tap + 1);   // next tap
                else if (c < 3)   LOADA(a[nxt], c + 1, 0);     // next chunk
                __builtin_amdgcn_s_setprio(1);
#pragma unroll
                for (int i = 0; i < 4; ++i)
#pragma unroll
                    for (int j = 0; j < 4; ++j)
#pragma unroll
                        for (int r = 0; r < 2; ++r)
                            acc[i][j][r] = __builtin_amdgcn_mfma_i32_16x16x64_i8(
                                a[cur][i], b[j][r], acc[i][j][r], 0, 0, 0);
                __builtin_amdgcn_s_setprio(0);
            }
        }
    }
#undef LOADA

    // ---- epilogue: dequant + bias + relu, fp32 NCHW
    const int h_out = h0 + rs;
#pragma unroll
    for (int i = 0; i < 4; ++i) {
        const int co = co_t * 128 + m_off + i * 16 + qd * 4;
        const float4 bv = *(const float4*)&bias[co];
        const float4 qv = *(const float4*)&qscale[co];
        const float bb[4] = {bv.x, bv.y, bv.z, bv.w};
        const float qq[4] = {qv.x, qv.y, qv.z, qv.w};
#pragma unroll
        for (int j = 0; j < 4; ++j) {
            const int w = j * 16 + l15;
            if (w < 56) {
#pragma unroll
                for (int rr = 0; rr < 2; ++rr) {
                    const size_t ob = (((size_t)n * CO + co) * HH + (h_out + rr)) * WW + w;
#pragma unroll
                    for (int r = 0; r < 4; ++r) {
                        float v = (float)acc[i][j][rr][r] * qq[r] + bb[r];
                        out[ob + (size_t)r * (HH * WW)] = v > 0.f ? v : 0.f;
                    }
                }
            }
        }
    }
}

// ================= launch =================
extern "C" void kernel_launch(void* const* d_in, const int* in_sizes, int n_in,
                              void* d_out, int out_size, void* d_ws, size_t ws_size,
                              hipStream_t stream) {
    const float* x      = (const float*)d_in[0];
    const float* gamma  = (const float*)d_in[1];
    const float* beta   = (const float*)d_in[2];
    const float* weight = (const float*)d_in[3];
    const float* bias   = (const float*)d_in[4];
    float* out = (float*)d_out;

    // workspace layout (16B aligned)
    double* part    = (double*)d_ws;                            // 32768 B
    float*  qscale  = (float*) ((char*)d_ws + 36864);           // 1024 B
    int8_t* wT      = (int8_t*)((char*)d_ws + 65536);           // 589824 B

    prep_kernel<<<2304, 256, 0, stream>>>(weight, x, wT, qscale, part);
    conv_kernel<<<896, 256, 0, stream>>>(wT, x, part, gamma, beta, bias, qscale, out);
}

// Round 4
// 322.860 us; speedup vs baseline: 1.4710x; 1.4710x over previous
//
#include <hip/hip_runtime.h>
#include <stdint.h>

#define NN 32
#define CI 256
#define CO 256
#define HH 56
#define WW 56
#define TPH 58
#define TPW 72
#define CNT (NN*HH*WW)

typedef int i32x4 __attribute__((ext_vector_type(4)));

// async global->LDS 16B (wave-uniform LDS base + lane*16)
__device__ __forceinline__ void gld16(const void* g, void* l) {
    __builtin_amdgcn_global_load_lds(
        (const __attribute__((address_space(1))) void*)(uintptr_t)g,
        (__attribute__((address_space(3))) void*)(uint32_t)(uintptr_t)l,
        16, 0, 0);
}

// ================= 1. per-channel stats, 8-way split over n ==============
__global__ void stats_part(const float* __restrict__ x, double* __restrict__ part) {
    const int c = blockIdx.x, sp = blockIdx.y;           // sp: 4 images each
    double s = 0.0, ss = 0.0;
    const size_t base = ((size_t)(sp * 4) * CI + c) * 3136;
    for (int idx = threadIdx.x; idx < 4 * 784; idx += 256) {
        int nl = idx / 784, q = idx % 784;
        const float4 v = *(const float4*)(x + base + (size_t)nl * CI * 3136 + q * 4);
        double a = v.x, b = v.y, cc = v.z, d = v.w;
        s  += (a + b) + (cc + d);
        ss += (a * a + b * b) + (cc * cc + d * d);
    }
    for (int off = 32; off > 0; off >>= 1) {
        s  += __shfl_down(s, off, 64);
        ss += __shfl_down(ss, off, 64);
    }
    __shared__ double red[8];
    int wid = threadIdx.x >> 6, lane = threadIdx.x & 63;
    if (lane == 0) { red[wid] = s; red[4 + wid] = ss; }
    __syncthreads();
    if (threadIdx.x == 0) {
        part[(sp * 256 + c) * 2]     = (red[0] + red[1]) + (red[2] + red[3]);
        part[(sp * 256 + c) * 2 + 1] = (red[4] + red[5]) + (red[6] + red[7]);
    }
}

// ================= 2. weight quant: per-co int8, layout [tap][chunk][co][ci64]
__global__ void wtrans_kernel(const float* __restrict__ w,
                              int8_t* __restrict__ wT,
                              float* __restrict__ qscale) {
    const int co = blockIdx.x;
    const float* wp = w + (size_t)co * 2304;
    float v[9], m = 0.f;
#pragma unroll
    for (int it = 0; it < 9; ++it) {
        v[it] = wp[threadIdx.x + it * 256];
        m = fmaxf(m, fabsf(v[it]));
    }
    for (int off = 32; off > 0; off >>= 1) m = fmaxf(m, __shfl_down(m, off, 64));
    __shared__ float red[4];
    __shared__ float qsh;
    int wid = threadIdx.x >> 6, lane = threadIdx.x & 63;
    if (lane == 0) red[wid] = m;
    __syncthreads();
    if (threadIdx.x == 0) {
        float mx = fmaxf(fmaxf(red[0], red[1]), fmaxf(red[2], red[3]));
        float q = (mx > 0.f) ? mx / 127.f : 1.f;
        qsh = q;
        qscale[co] = q;
    }
    __syncthreads();
    const float q = qsh;
#pragma unroll
    for (int it = 0; it < 9; ++it) {
        int idx = threadIdx.x + it * 256;
        int ci = idx / 9, tap = idx % 9;
        int chunk = ci >> 6, cis = ci & 63;
        int iq = __float2int_rn(v[it] / q);
        iq = iq > 127 ? 127 : (iq < -127 ? -127 : iq);
        wT[((size_t)(tap * 4 + chunk) * 256 + co) * 64 + cis] = (int8_t)iq;
    }
}

// ========== 3. fused stats-final + ternarize + halo: NCHW -> padded CHUNK-MAJOR
// tp layout: [n][row58][chunk4][wp72][ci64]  (per-chunk stage is contiguous)
// grid (58, 32): blockIdx.x = padded row (0 and 57 are halo rows)
__global__ void ternarize_kernel(const float* __restrict__ x,
                                 const double* __restrict__ part,
                                 const float* __restrict__ gamma,
                                 const float* __restrict__ beta,
                                 int8_t* __restrict__ tp) {
    const int h = blockIdx.x, n = blockIdx.y;
    i32x4* rowp = (i32x4*)(tp + ((size_t)n * TPH + h) * TPW * CI);
    if (h == 0 || h == TPH - 1) {                      // halo rows: zero
        const i32x4 z = {0, 0, 0, 0};
        for (int p = threadIdx.x; p < TPW * 16; p += 256) rowp[p] = z;
        return;
    }
    // per-block finalize of channel stats (replaces stats_final kernel)
    __shared__ double Ssc[256], Ssh[256];
    {
        const int c = threadIdx.x;
        double S = 0.0, SS = 0.0;
#pragma unroll
        for (int sp = 0; sp < 8; ++sp) {
            S  += part[(sp * 256 + c) * 2];
            SS += part[(sp * 256 + c) * 2 + 1];
        }
        double mean = S / (double)CNT;
        double var  = SS / (double)CNT - mean * mean;
        double invstd = 1.0 / sqrt(var + 1e-4);
        double scale = (double)gamma[c] * invstd;
        Ssc[c] = scale;
        Ssh[c] = (double)beta[c] - mean * scale;
    }
    __shared__ int8_t L[56 * 260];                     // [w][ci], stride 260
    __syncthreads();
    const int hin = h - 1;
    const size_t xb = ((size_t)n * CI) * 3136 + (size_t)hin * 56;
    // vectorized read: 256 ci x 14 float4
    for (int idx = threadIdx.x; idx < CI * 14; idx += 256) {
        int ci = idx / 14, w4 = idx - ci * 14;
        const float4 v = *(const float4*)(x + xb + (size_t)ci * 3136 + w4 * 4);
        const double sc = Ssc[ci], sh = Ssh[ci];
        const int w = w4 * 4;
        L[(w + 0) * 260 + ci] = (fma(sc, (double)v.x, sh) > 0.0) ? (int8_t)1 : (int8_t)-1;
        L[(w + 1) * 260 + ci] = (fma(sc, (double)v.y, sh) > 0.0) ? (int8_t)1 : (int8_t)-1;
        L[(w + 2) * 260 + ci] = (fma(sc, (double)v.z, sh) > 0.0) ? (int8_t)1 : (int8_t)-1;
        L[(w + 3) * 260 + ci] = (fma(sc, (double)v.w, sh) > 0.0) ? (int8_t)1 : (int8_t)-1;
    }
    __syncthreads();
    for (int p = threadIdx.x; p < TPW * 16; p += 256) {
        int wo = p >> 4, c16 = p & 15;
        i32x4 v = {0, 0, 0, 0};
        if (wo >= 1 && wo <= 56) {
            const int* lp = (const int*)&L[(wo - 1) * 260 + c16 * 16];
            v.x = lp[0]; v.y = lp[1]; v.z = lp[2]; v.w = lp[3];
        }
        // chunk-major store: [chunk][wp][s]
        const int chunk = c16 >> 2, s = c16 & 3;
        rowp[chunk * 288 + wo * 4 + s] = v;
    }
}

// ================= 4. implicit-GEMM conv, int8 MFMA, dbuf LDS =============
// grid (2, 28, 32); block 256 = 4 waves; tile 128co x (2 rows x 64w)
// B LDS: per ci64-chunk [row4][wp72][64B], ci-16B-slots XOR-swizzled by wp,
// swizzle applied on the (now CONTIGUOUS chunk-major) global source address.
__device__ __forceinline__ void stage_chunk(const int8_t* __restrict__ g0,
                                            int8_t* lbuf, int chunk, int tid) {
#pragma unroll
    for (int j = 0; j < 5; ++j) {
        int p = tid + j * 256;                      // 0..1151
        if (j < 4 || tid < 128) {
            int row = p / 288, rem = p - row * 288;
            int wp = rem >> 2, s = rem & 3;
            int g = (s - wp) & 3;
            gld16(g0 + (size_t)row * TPW * CI + chunk * (TPW * 64) + wp * 64 + g * 16,
                  lbuf + p * 16);
        }
    }
}

__launch_bounds__(256, 2)
__global__ void conv_kernel(const int8_t* __restrict__ wT,
                            const int8_t* __restrict__ tp,
                            const float* __restrict__ bias,
                            const float* __restrict__ qscale,
                            float* __restrict__ out) {
    const int co_t = blockIdx.x;
    const int h0   = blockIdx.y * 2;
    const int n    = blockIdx.z;
    const int tid  = threadIdx.x;
    const int lane = tid & 63, wid = tid >> 6;
    const int l15 = lane & 15, qd = lane >> 4;
    const int m_off = (wid & 1) * 64;
    const int rowsel = wid >> 1;

    __shared__ int8_t Bsh[2 * 4 * TPW * 64];        // 36864 B, double-buffered

    i32x4 acc[4][4];
#pragma unroll
    for (int i = 0; i < 4; ++i)
#pragma unroll
        for (int j = 0; j < 4; ++j) acc[i][j] = (i32x4){0, 0, 0, 0};

    const int8_t* g0 = tp + ((size_t)n * TPH + h0) * TPW * CI;

    stage_chunk(g0, Bsh, 0, tid);
    for (int c = 0; c < 4; ++c) {
        __syncthreads();                            // stage(c) complete; compute(c-1) done
        if (c < 3) stage_chunk(g0, Bsh + ((c + 1) & 1) * 18432, c + 1, tid);
        const int8_t* lb = Bsh + (c & 1) * 18432;
#pragma unroll
        for (int kh = 0; kh < 3; ++kh) {
            const int brow = (rowsel + kh) * TPW;
#pragma unroll
            for (int kw = 0; kw < 3; ++kw) {
                const int tap = kh * 3 + kw;
                const i32x4* ap = (const i32x4*)(wT +
                    ((size_t)(tap * 4 + c) * 256 + co_t * 128 + m_off) * 64);
                i32x4 a[4], b[4];
#pragma unroll
                for (int i = 0; i < 4; ++i)
                    a[i] = ap[(i * 16 + l15) * 4 + qd];
#pragma unroll
                for (int j = 0; j < 4; ++j) {
                    int wp = j * 16 + l15 + kw;
                    int slot = (qd + wp) & 3;
                    b[j] = *(const i32x4*)&lb[(brow + wp) * 64 + slot * 16];
                }
#pragma unroll
                for (int i = 0; i < 4; ++i)
#pragma unroll
                    for (int j = 0; j < 4; ++j)
                        acc[i][j] = __builtin_amdgcn_mfma_i32_16x16x64_i8(
                            a[i], b[j], acc[i][j], 0, 0, 0);
            }
        }
    }

    // epilogue: dequant + bias + relu, fp32 NCHW
    const int h_out = h0 + rowsel;
#pragma unroll
    for (int i = 0; i < 4; ++i) {
        const int co = co_t * 128 + m_off + i * 16 + qd * 4;
        const float4 bv = *(const float4*)&bias[co];
        const float4 qv = *(const float4*)&qscale[co];
        const float bb[4] = {bv.x, bv.y, bv.z, bv.w};
        const float qq[4] = {qv.x, qv.y, qv.z, qv.w};
#pragma unroll
        for (int j = 0; j < 4; ++j) {
            const int w = j * 16 + l15;
            if (w < 56) {
                const size_t ob = (((size_t)n * CO + co) * HH + h_out) * WW + w;
#pragma unroll
                for (int r = 0; r < 4; ++r) {
                    float v = (float)acc[i][j][r] * qq[r] + bb[r];
                    out[ob + (size_t)r * (HH * WW)] = v > 0.f ? v : 0.f;
                }
            }
        }
    }
}

// ================= launch =================
extern "C" void kernel_launch(void* const* d_in, const int* in_sizes, int n_in,
                              void* d_out, int out_size, void* d_ws, size_t ws_size,
                              hipStream_t stream) {
    const float* x      = (const float*)d_in[0];
    const float* gamma  = (const float*)d_in[1];
    const float* beta   = (const float*)d_in[2];
    const float* weight = (const float*)d_in[3];
    const float* bias   = (const float*)d_in[4];
    float* out = (float*)d_out;

    // workspace layout (16B aligned)
    double* part    = (double*)d_ws;                            // 32768 B
    float*  qscale  = (float*) ((char*)d_ws + 36864);           // 1024 B
    int8_t* wT      = (int8_t*)((char*)d_ws + 65536);           // 589824 B
    int8_t* tp      = (int8_t*)((char*)d_ws + 1048576);         // 34209792 B

    wtrans_kernel<<<256, 256, 0, stream>>>(weight, wT, qscale);
    stats_part<<<dim3(256, 8), 256, 0, stream>>>(x, part);
    ternarize_kernel<<<dim3(TPH, NN), 256, 0, stream>>>(x, part, gamma, beta, tp);
    conv_kernel<<<dim3(2, 28, NN), 256, 0, stream>>>(wT, tp, bias, qscale, out);
}

// Round 5
// 289.434 us; speedup vs baseline: 1.6409x; 1.1155x over previous
//
#include <hip/hip_runtime.h>
#include <stdint.h>

#define NN 32
#define CI 256
#define CO 256
#define HH 56
#define WW 56
#define TPH 58
#define TPW 72
#define CNT (NN*HH*WW)

typedef int i32x4 __attribute__((ext_vector_type(4)));

// async global->LDS 16B (wave-uniform LDS base + lane*16)
__device__ __forceinline__ void gld16(const void* g, void* l) {
    __builtin_amdgcn_global_load_lds(
        (const __attribute__((address_space(1))) void*)(uintptr_t)g,
        (__attribute__((address_space(3))) void*)(uint32_t)(uintptr_t)l,
        16, 0, 0);
}

// ======== 1. prep: weight-quant (blocks 0..255) + channel stats (256..2303)
__global__ void prep_kernel(const float* __restrict__ w,
                            const float* __restrict__ x,
                            int8_t* __restrict__ wT,
                            float* __restrict__ qscale,
                            double* __restrict__ part) {
    const int bid = blockIdx.x;
    if (bid < 256) {
        // ---- weight quant: per-co int8, layout [tap][chunk][co][ci64]
        const int co = bid;
        const float* wp = w + (size_t)co * 2304;
        float v[9], m = 0.f;
#pragma unroll
        for (int it = 0; it < 9; ++it) {
            v[it] = wp[threadIdx.x + it * 256];
            m = fmaxf(m, fabsf(v[it]));
        }
        for (int off = 32; off > 0; off >>= 1) m = fmaxf(m, __shfl_down(m, off, 64));
        __shared__ float redf[4];
        __shared__ float qsh;
        int wid = threadIdx.x >> 6, lane = threadIdx.x & 63;
        if (lane == 0) redf[wid] = m;
        __syncthreads();
        if (threadIdx.x == 0) {
            float mx = fmaxf(fmaxf(redf[0], redf[1]), fmaxf(redf[2], redf[3]));
            float q = (mx > 0.f) ? mx / 127.f : 1.f;
            qsh = q;
            qscale[co] = q;
        }
        __syncthreads();
        const float q = qsh;
#pragma unroll
        for (int it = 0; it < 9; ++it) {
            int idx = threadIdx.x + it * 256;
            int ci = idx / 9, tap = idx % 9;
            int chunk = ci >> 6, cis = ci & 63;
            int iq = __float2int_rn(v[it] / q);
            iq = iq > 127 ? 127 : (iq < -127 ? -127 : iq);
            wT[((size_t)(tap * 4 + chunk) * 256 + co) * 64 + cis] = (int8_t)iq;
        }
    } else {
        // ---- per-channel stats partials, 8-way split over n (4 images each)
        const int idx = bid - 256;
        const int c = idx & 255, sp = idx >> 8;
        double s = 0.0, ss = 0.0;
        const size_t base = ((size_t)(sp * 4) * CI + c) * 3136;
        for (int i = threadIdx.x; i < 4 * 784; i += 256) {
            int nl = i / 784, qq = i % 784;
            const float4 v = *(const float4*)(x + base + (size_t)nl * CI * 3136 + qq * 4);
            double a = v.x, b = v.y, cc = v.z, d = v.w;
            s  += (a + b) + (cc + d);
            ss += (a * a + b * b) + (cc * cc + d * d);
        }
        for (int off = 32; off > 0; off >>= 1) {
            s  += __shfl_down(s, off, 64);
            ss += __shfl_down(ss, off, 64);
        }
        __shared__ double redd[8];
        int wid = threadIdx.x >> 6, lane = threadIdx.x & 63;
        if (lane == 0) { redd[wid] = s; redd[4 + wid] = ss; }
        __syncthreads();
        if (threadIdx.x == 0) {
            part[(sp * 256 + c) * 2]     = (redd[0] + redd[1]) + (redd[2] + redd[3]);
            part[(sp * 256 + c) * 2 + 1] = (redd[4] + redd[5]) + (redd[6] + redd[7]);
        }
    }
}

// ========== 2. fused stats-final + ternarize + halo: NCHW -> padded CHUNK-MAJOR
// tp layout: [n][row58][chunk4][wp72][ci64]  (per-chunk stage is contiguous)
// grid (58, 32): blockIdx.x = padded row (0 and 57 are halo rows)
__global__ void ternarize_kernel(const float* __restrict__ x,
                                 const double* __restrict__ part,
                                 const float* __restrict__ gamma,
                                 const float* __restrict__ beta,
                                 int8_t* __restrict__ tp) {
    const int h = blockIdx.x, n = blockIdx.y;
    i32x4* rowp = (i32x4*)(tp + ((size_t)n * TPH + h) * TPW * CI);
    if (h == 0 || h == TPH - 1) {                      // halo rows: zero
        const i32x4 z = {0, 0, 0, 0};
        for (int p = threadIdx.x; p < TPW * 16; p += 256) rowp[p] = z;
        return;
    }
    // per-block finalize of channel stats
    __shared__ double Ssc[256], Ssh[256];
    {
        const int c = threadIdx.x;
        double S = 0.0, SS = 0.0;
#pragma unroll
        for (int sp = 0; sp < 8; ++sp) {
            S  += part[(sp * 256 + c) * 2];
            SS += part[(sp * 256 + c) * 2 + 1];
        }
        double mean = S / (double)CNT;
        double var  = SS / (double)CNT - mean * mean;
        double invstd = 1.0 / sqrt(var + 1e-4);
        double scale = (double)gamma[c] * invstd;
        Ssc[c] = scale;
        Ssh[c] = (double)beta[c] - mean * scale;
    }
    __shared__ int8_t L[56 * 260];                     // [w][ci], stride 260
    __syncthreads();
    const int hin = h - 1;
    const size_t xb = ((size_t)n * CI) * 3136 + (size_t)hin * 56;
    // vectorized read: 256 ci x 14 float4
    for (int idx = threadIdx.x; idx < CI * 14; idx += 256) {
        int ci = idx / 14, w4 = idx - ci * 14;
        const float4 v = *(const float4*)(x + xb + (size_t)ci * 3136 + w4 * 4);
        const double sc = Ssc[ci], sh = Ssh[ci];
        const int w = w4 * 4;
        L[(w + 0) * 260 + ci] = (fma(sc, (double)v.x, sh) > 0.0) ? (int8_t)1 : (int8_t)-1;
        L[(w + 1) * 260 + ci] = (fma(sc, (double)v.y, sh) > 0.0) ? (int8_t)1 : (int8_t)-1;
        L[(w + 2) * 260 + ci] = (fma(sc, (double)v.z, sh) > 0.0) ? (int8_t)1 : (int8_t)-1;
        L[(w + 3) * 260 + ci] = (fma(sc, (double)v.w, sh) > 0.0) ? (int8_t)1 : (int8_t)-1;
    }
    __syncthreads();
    for (int p = threadIdx.x; p < TPW * 16; p += 256) {
        int wo = p >> 4, c16 = p & 15;
        i32x4 v = {0, 0, 0, 0};
        if (wo >= 1 && wo <= 56) {
            const int* lp = (const int*)&L[(wo - 1) * 260 + c16 * 16];
            v.x = lp[0]; v.y = lp[1]; v.z = lp[2]; v.w = lp[3];
        }
        // chunk-major store: [chunk][wp][s]
        const int chunk = c16 >> 2, s = c16 & 3;
        rowp[chunk * 288 + wo * 4 + s] = v;
    }
}

// ================= 3. implicit-GEMM conv, int8 MFMA ======================
// grid 1792 flat (XCD-swizzled); block 256 = 4 waves; tile 128co x 2 rows x 64w.
// SINGLE stage of the ENTIRE B tile (4 rows x 4 chunks = 73728 B), ONE barrier,
// then 36 tap-iters whose vmcnt FIFO holds ONLY A loads (a[2] rotation works).
// LDS layout [row4][chunk4][wp72][4 slots x16B]; ci-slot XOR-swizzle on the
// global source (g=(s-wp)&3), read back at slot=(qd+wp)&3.
#define BUF_B (4 * 4 * TPW * 64)                       // 73728 B

__launch_bounds__(256, 2)
__global__ void conv_kernel(const int8_t* __restrict__ wT,
                            const int8_t* __restrict__ tp,
                            const float* __restrict__ bias,
                            const float* __restrict__ qscale,
                            float* __restrict__ out) {
    // bijective XCD swizzle: 1792 = 8 * 224 -> each XCD gets 4 contiguous
    // images; co-pair + adjacent rows land on the same L2.
    const int bid = blockIdx.x;
    const int lin = (bid & 7) * 224 + (bid >> 3);
    const int co_t = lin & 1;
    const int yb   = (lin >> 1) % 28;
    const int n    = lin / 56;
    const int h0   = yb * 2;

    const int tid  = threadIdx.x;
    const int lane = tid & 63, wid = tid >> 6;
    const int l15 = lane & 15, qd = lane >> 4;
    const int m_off = (wid & 1) * 64;
    const int rowsel = wid >> 1;
    const int aoff = l15 * 64 + qd * 16;               // per-lane A offset

    __shared__ __align__(16) int8_t Bsh[BUF_B];

    i32x4 acc[4][4];
#pragma unroll
    for (int i = 0; i < 4; ++i)
#pragma unroll
        for (int j = 0; j < 4; ++j) acc[i][j] = (i32x4){0, 0, 0, 0};

    // ---- single full-tile stage: 4 rows x 18432 B contiguous each
    {
        const int8_t* g0 = tp + ((size_t)n * TPH + h0) * TPW * CI;
#pragma unroll
        for (int j = 0; j < 18; ++j) {
            int p = tid + j * 256;                     // 0..4607
            int row = p / 1152, rem = p - row * 1152;
            int chunk = rem / 288, rem2 = rem - chunk * 288;
            int wp = rem2 >> 2, s = rem2 & 3;
            int g = (s - wp) & 3;
            gld16(g0 + (size_t)row * (TPW * CI) + chunk * (TPW * 64) + wp * 64 + g * 16,
                  Bsh + p * 16);
        }
    }

#define LOADA(dst, cc_, tap_) do {                                              \
    const int8_t* ap_ = wT +                                                    \
        (((size_t)((tap_) * 4 + (cc_)) * 256 + co_t * 128 + m_off) << 6) + aoff;\
    dst[0] = *(const i32x4*)(ap_);                                              \
    dst[1] = *(const i32x4*)(ap_ + 1024);                                       \
    dst[2] = *(const i32x4*)(ap_ + 2048);                                       \
    dst[3] = *(const i32x4*)(ap_ + 3072);                                       \
} while (0)

    i32x4 a[2][4];
    LOADA(a[0], 0, 0);                                 // overlaps barrier wait
    __syncthreads();                                   // stage complete (vmcnt drain)

    for (int c2 = 0; c2 < 2; ++c2) {
#pragma unroll
        for (int cc = 0; cc < 2; ++cc) {
            const int c = c2 * 2 + cc;
#pragma unroll
            for (int tap = 0; tap < 9; ++tap) {
                const int kh = tap / 3, kw = tap % 3;
                const int cur = (cc * 9 + tap) & 1, nxt = cur ^ 1;  // static
                i32x4 b[4];
#pragma unroll
                for (int j = 0; j < 4; ++j) {
                    const int wp = j * 16 + l15 + kw;
                    const int slot = (qd + wp) & 3;
                    b[j] = *(const i32x4*)&Bsh[
                        (((rowsel + kh) * 4 + c) * TPW + wp) * 64 + slot * 16];
                }
                if (tap < 8)      LOADA(a[nxt], c, tap + 1);   // next tap
                else if (c < 3)   LOADA(a[nxt], c + 1, 0);     // next chunk
                __builtin_amdgcn_s_setprio(1);
#pragma unroll
                for (int i = 0; i < 4; ++i)
#pragma unroll
                    for (int j = 0; j < 4; ++j)
                        acc[i][j] = __builtin_amdgcn_mfma_i32_16x16x64_i8(
                            a[cur][i], b[j], acc[i][j], 0, 0, 0);
                __builtin_amdgcn_s_setprio(0);
            }
        }
    }
#undef LOADA

    // ---- epilogue: dequant + bias + relu, fp32 NCHW
    const int h_out = h0 + rowsel;
#pragma unroll
    for (int i = 0; i < 4; ++i) {
        const int co = co_t * 128 + m_off + i * 16 + qd * 4;
        const float4 bv = *(const float4*)&bias[co];
        const float4 qv = *(const float4*)&qscale[co];
        const float bb[4] = {bv.x, bv.y, bv.z, bv.w};
        const float qq[4] = {qv.x, qv.y, qv.z, qv.w};
#pragma unroll
        for (int j = 0; j < 4; ++j) {
            const int w = j * 16 + l15;
            if (w < 56) {
                const size_t ob = (((size_t)n * CO + co) * HH + h_out) * WW + w;
#pragma unroll
                for (int r = 0; r < 4; ++r) {
                    float v = (float)acc[i][j][r] * qq[r] + bb[r];
                    out[ob + (size_t)r * (HH * WW)] = v > 0.f ? v : 0.f;
                }
            }
        }
    }
}

// ================= launch =================
extern "C" void kernel_launch(void* const* d_in, const int* in_sizes, int n_in,
                              void* d_out, int out_size, void* d_ws, size_t ws_size,
                              hipStream_t stream) {
    const float* x      = (const float*)d_in[0];
    const float* gamma  = (const float*)d_in[1];
    const float* beta   = (const float*)d_in[2];
    const float* weight = (const float*)d_in[3];
    const float* bias   = (const float*)d_in[4];
    float* out = (float*)d_out;

    // workspace layout (16B aligned)
    double* part    = (double*)d_ws;                            // 32768 B
    float*  qscale  = (float*) ((char*)d_ws + 36864);           // 1024 B
    int8_t* wT      = (int8_t*)((char*)d_ws + 65536);           // 589824 B
    int8_t* tp      = (int8_t*)((char*)d_ws + 1048576);         // 34209792 B

    prep_kernel<<<2304, 256, 0, stream>>>(weight, x, wT, qscale, part);
    ternarize_kernel<<<dim3(TPH, NN), 256, 0, stream>>>(x, part, gamma, beta, tp);
    conv_kernel<<<1792, 256, 0, stream>>>(wT, tp, bias, qscale, out);
}

// Round 8
// 275.110 us; speedup vs baseline: 1.7263x; 1.0521x over previous
//
#include <hip/hip_runtime.h>
#include <stdint.h>

#define NN 32
#define CI 256
#define CO 256
#define HH 56
#define WW 56
#define TPH 58
#define TPW 72
#define CNT (NN*HH*WW)

typedef int i32x4 __attribute__((ext_vector_type(4)));

// async global->LDS 16B (wave-uniform LDS base + lane*16)
__device__ __forceinline__ void gld16(const void* g, void* l) {
    __builtin_amdgcn_global_load_lds(
        (const __attribute__((address_space(1))) void*)(uintptr_t)g,
        (__attribute__((address_space(3))) void*)(uint32_t)(uintptr_t)l,
        16, 0, 0);
}

// ======== 1. prep: weight-quant (blocks 0..255) + channel stats (256..2303)
__global__ void prep_kernel(const float* __restrict__ w,
                            const float* __restrict__ x,
                            int8_t* __restrict__ wT,
                            float* __restrict__ qscale,
                            double* __restrict__ part) {
    const int bid = blockIdx.x;
    if (bid < 256) {
        // ---- weight quant: per-co int8, layout [tap][chunk][co][ci64]
        const int co = bid;
        const float* wp = w + (size_t)co * 2304;
        float v[9], m = 0.f;
#pragma unroll
        for (int it = 0; it < 9; ++it) {
            v[it] = wp[threadIdx.x + it * 256];
            m = fmaxf(m, fabsf(v[it]));
        }
        for (int off = 32; off > 0; off >>= 1) m = fmaxf(m, __shfl_down(m, off, 64));
        __shared__ float redf[4];
        __shared__ float qsh;
        int wid = threadIdx.x >> 6, lane = threadIdx.x & 63;
        if (lane == 0) redf[wid] = m;
        __syncthreads();
        if (threadIdx.x == 0) {
            float mx = fmaxf(fmaxf(redf[0], redf[1]), fmaxf(redf[2], redf[3]));
            float q = (mx > 0.f) ? mx / 127.f : 1.f;
            qsh = q;
            qscale[co] = q;
        }
        __syncthreads();
        const float q = qsh;
#pragma unroll
        for (int it = 0; it < 9; ++it) {
            int idx = threadIdx.x + it * 256;
            int ci = idx / 9, tap = idx % 9;
            int chunk = ci >> 6, cis = ci & 63;
            int iq = __float2int_rn(v[it] / q);
            iq = iq > 127 ? 127 : (iq < -127 ? -127 : iq);
            wT[((size_t)(tap * 4 + chunk) * 256 + co) * 64 + cis] = (int8_t)iq;
        }
    } else {
        // ---- per-channel stats partials, 8-way split over n (4 images each)
        const int idx = bid - 256;
        const int c = idx & 255, sp = idx >> 8;
        double s = 0.0, ss = 0.0;
        const size_t base = ((size_t)(sp * 4) * CI + c) * 3136;
        for (int i = threadIdx.x; i < 4 * 784; i += 256) {
            int nl = i / 784, qq = i % 784;
            const float4 v = *(const float4*)(x + base + (size_t)nl * CI * 3136 + qq * 4);
            double a = v.x, b = v.y, cc = v.z, d = v.w;
            s  += (a + b) + (cc + d);
            ss += (a * a + b * b) + (cc * cc + d * d);
        }
        for (int off = 32; off > 0; off >>= 1) {
            s  += __shfl_down(s, off, 64);
            ss += __shfl_down(ss, off, 64);
        }
        __shared__ double redd[8];
        int wid = threadIdx.x >> 6, lane = threadIdx.x & 63;
        if (lane == 0) { redd[wid] = s; redd[4 + wid] = ss; }
        __syncthreads();
        if (threadIdx.x == 0) {
            part[(sp * 256 + c) * 2]     = (redd[0] + redd[1]) + (redd[2] + redd[3]);
            part[(sp * 256 + c) * 2 + 1] = (redd[4] + redd[5]) + (redd[6] + redd[7]);
        }
    }
}

// ========== 2. fused stats-final + ternarize + halo: NCHW -> padded CHUNK-MAJOR
// tp layout: [n][row58][chunk4][wp72][ci64]  (per-chunk stage is contiguous)
// grid (58, 32): blockIdx.x = padded row (0 and 57 are halo rows)
__global__ void ternarize_kernel(const float* __restrict__ x,
                                 const double* __restrict__ part,
                                 const float* __restrict__ gamma,
                                 const float* __restrict__ beta,
                                 int8_t* __restrict__ tp) {
    const int h = blockIdx.x, n = blockIdx.y;
    i32x4* rowp = (i32x4*)(tp + ((size_t)n * TPH + h) * TPW * CI);
    if (h == 0 || h == TPH - 1) {                      // halo rows: zero
        const i32x4 z = {0, 0, 0, 0};
        for (int p = threadIdx.x; p < TPW * 16; p += 256) rowp[p] = z;
        return;
    }
    // per-block finalize of channel stats
    __shared__ double Ssc[256], Ssh[256];
    {
        const int c = threadIdx.x;
        double S = 0.0, SS = 0.0;
#pragma unroll
        for (int sp = 0; sp < 8; ++sp) {
            S  += part[(sp * 256 + c) * 2];
            SS += part[(sp * 256 + c) * 2 + 1];
        }
        double mean = S / (double)CNT;
        double var  = SS / (double)CNT - mean * mean;
        double invstd = 1.0 / sqrt(var + 1e-4);
        double scale = (double)gamma[c] * invstd;
        Ssc[c] = scale;
        Ssh[c] = (double)beta[c] - mean * scale;
    }
    __shared__ int8_t L[56 * 260];                     // [w][ci], stride 260
    __syncthreads();
    const int hin = h - 1;
    const size_t xb = ((size_t)n * CI) * 3136 + (size_t)hin * 56;
    // vectorized read: 256 ci x 14 float4
    for (int idx = threadIdx.x; idx < CI * 14; idx += 256) {
        int ci = idx / 14, w4 = idx - ci * 14;
        const float4 v = *(const float4*)(x + xb + (size_t)ci * 3136 + w4 * 4);
        const double sc = Ssc[ci], sh = Ssh[ci];
        const int w = w4 * 4;
        L[(w + 0) * 260 + ci] = (fma(sc, (double)v.x, sh) > 0.0) ? (int8_t)1 : (int8_t)-1;
        L[(w + 1) * 260 + ci] = (fma(sc, (double)v.y, sh) > 0.0) ? (int8_t)1 : (int8_t)-1;
        L[(w + 2) * 260 + ci] = (fma(sc, (double)v.z, sh) > 0.0) ? (int8_t)1 : (int8_t)-1;
        L[(w + 3) * 260 + ci] = (fma(sc, (double)v.w, sh) > 0.0) ? (int8_t)1 : (int8_t)-1;
    }
    __syncthreads();
    for (int p = threadIdx.x; p < TPW * 16; p += 256) {
        int wo = p >> 4, c16 = p & 15;
        i32x4 v = {0, 0, 0, 0};
        if (wo >= 1 && wo <= 56) {
            const int* lp = (const int*)&L[(wo - 1) * 260 + c16 * 16];
            v.x = lp[0]; v.y = lp[1]; v.z = lp[2]; v.w = lp[3];
        }
        // chunk-major store: [chunk][wp][s]
        const int chunk = c16 >> 2, s = c16 & 3;
        rowp[chunk * 288 + wo * 4 + s] = v;
    }
}

// ================= 3. implicit-GEMM conv, int8 MFMA ======================
// grid 1792 flat (XCD-swizzled); block 256 = 4 waves; tile 128co x 2 rows x 64w.
// SINGLE stage of the ENTIRE B tile (73728 B), ONE barrier; post-barrier the
// vmcnt FIFO holds ONLY A loads, software-pipelined THREE taps ahead in a
// ring of FOUR (depth < ring size -> no slot collision; r6's depth-4 bug).
#define BUF_B (4 * 4 * TPW * 64)                       // 73728 B

__launch_bounds__(256, 2)
__global__ void conv_kernel(const int8_t* __restrict__ wT,
                            const int8_t* __restrict__ tp,
                            const float* __restrict__ bias,
                            const float* __restrict__ qscale,
                            float* __restrict__ out) {
    // bijective XCD swizzle: 1792 = 8 * 224 -> each XCD gets 4 contiguous
    // images; co-pair + adjacent rows land on the same L2.
    const int bid = blockIdx.x;
    const int lin0 = (bid & 7) * 224 + (bid >> 3);
    const int co_t = lin0 & 1;
    const int yb   = (lin0 >> 1) % 28;
    const int n    = lin0 / 56;
    const int h0   = yb * 2;

    const int tid  = threadIdx.x;
    const int lane = tid & 63, wid = tid >> 6;
    const int l15 = lane & 15, qd = lane >> 4;
    const int m_off = (wid & 1) * 64;
    const int rowsel = wid >> 1;
    const int aoff = l15 * 64 + qd * 16;               // per-lane A offset

    __shared__ __align__(16) int8_t Bsh[BUF_B];

    i32x4 acc[4][4];
#pragma unroll
    for (int i = 0; i < 4; ++i)
#pragma unroll
        for (int j = 0; j < 4; ++j) acc[i][j] = (i32x4){0, 0, 0, 0};

    // ---- single full-tile stage: 4 rows x 18432 B contiguous each
    {
        const int8_t* g0 = tp + ((size_t)n * TPH + h0) * TPW * CI;
#pragma unroll
        for (int j = 0; j < 18; ++j) {
            int p = tid + j * 256;                     // 0..4607
            int row = p / 1152, rem = p - row * 1152;
            int chunk = rem / 288, rem2 = rem - chunk * 288;
            int wp = rem2 >> 2, s = rem2 & 3;
            int g = (s - wp) & 3;
            gld16(g0 + (size_t)row * (TPW * CI) + chunk * (TPW * 64) + wp * 64 + g * 16,
                  Bsh + p * 16);
        }
    }

#define LOADA(dst, cc_, tap_) do {                                              \
    const int8_t* ap_ = wT +                                                    \
        (((size_t)((tap_) * 4 + (cc_)) * 256 + co_t * 128 + m_off) << 6) + aoff;\
    dst[0] = *(const i32x4*)(ap_);                                              \
    dst[1] = *(const i32x4*)(ap_ + 1024);                                       \
    dst[2] = *(const i32x4*)(ap_ + 2048);                                       \
    dst[3] = *(const i32x4*)(ap_ + 3072);                                       \
} while (0)

    i32x4 a[4][4];
    // prologue: A for taps 0..2 in flight (depth 3; regs survive barrier drain)
    LOADA(a[0], 0, 0);
    LOADA(a[1], 0, 1);
    LOADA(a[2], 0, 2);
    __syncthreads();                                   // stage complete (vmcnt drain)

#pragma unroll
    for (int c = 0; c < 4; ++c) {
#pragma unroll
        for (int tap = 0; tap < 9; ++tap) {
            const int lint = c * 9 + tap;              // compile-time
            const int cur = lint & 3;
            const int kh = tap / 3, kw = tap % 3;
            if (lint < 33) {                           // prefetch 3 taps ahead
                const int nl = lint + 3;               // (nl&3) != cur always
                LOADA(a[nl & 3], nl / 9, nl % 9);
            }
            i32x4 b[4];
#pragma unroll
            for (int j = 0; j < 4; ++j) {
                const int wp = j * 16 + l15 + kw;
                const int slot = (qd + wp) & 3;
                b[j] = *(const i32x4*)&Bsh[
                    (((rowsel + kh) * 4 + c) * TPW + wp) * 64 + slot * 16];
            }
            __builtin_amdgcn_s_setprio(1);
#pragma unroll
            for (int i = 0; i < 4; ++i)
#pragma unroll
                for (int j = 0; j < 4; ++j)
                    acc[i][j] = __builtin_amdgcn_mfma_i32_16x16x64_i8(
                        a[cur][i], b[j], acc[i][j], 0, 0, 0);
            __builtin_amdgcn_s_setprio(0);
        }
    }
#undef LOADA

    // ---- epilogue: dequant + bias + relu, fp32 NCHW
    const int h_out = h0 + rowsel;
#pragma unroll
    for (int i = 0; i < 4; ++i) {
        const int co = co_t * 128 + m_off + i * 16 + qd * 4;
        const float4 bv = *(const float4*)&bias[co];
        const float4 qv = *(const float4*)&qscale[co];
        const float bb[4] = {bv.x, bv.y, bv.z, bv.w};
        const float qq[4] = {qv.x, qv.y, qv.z, qv.w};
#pragma unroll
        for (int j = 0; j < 4; ++j) {
            const int w = j * 16 + l15;
            if (w < 56) {
                const size_t ob = (((size_t)n * CO + co) * HH + h_out) * WW + w;
#pragma unroll
                for (int r = 0; r < 4; ++r) {
                    float v = (float)acc[i][j][r] * qq[r] + bb[r];
                    out[ob + (size_t)r * (HH * WW)] = v > 0.f ? v : 0.f;
                }
            }
        }
    }
}

// ================= launch =================
extern "C" void kernel_launch(void* const* d_in, const int* in_sizes, int n_in,
                              void* d_out, int out_size, void* d_ws, size_t ws_size,
                              hipStream_t stream) {
    const float* x      = (const float*)d_in[0];
    const float* gamma  = (const float*)d_in[1];
    const float* beta   = (const float*)d_in[2];
    const float* weight = (const float*)d_in[3];
    const float* bias   = (const float*)d_in[4];
    float* out = (float*)d_out;

    // workspace layout (16B aligned)
    double* part    = (double*)d_ws;                            // 32768 B
    float*  qscale  = (float*) ((char*)d_ws + 36864);           // 1024 B
    int8_t* wT      = (int8_t*)((char*)d_ws + 65536);           // 589824 B
    int8_t* tp      = (int8_t*)((char*)d_ws + 1048576);         // 34209792 B

    prep_kernel<<<2304, 256, 0, stream>>>(weight, x, wT, qscale, part);
    ternarize_kernel<<<dim3(TPH, NN), 256, 0, stream>>>(x, part, gamma, beta, tp);
    conv_kernel<<<1792, 256, 0, stream>>>(wT, tp, bias, qscale, out);
}